// Round 13
// baseline (670.493 us; speedup 1.0000x reference)
//
#include <hip/hip_runtime.h>
#include <hip/hip_bf16.h>

#define N_NODES 100000
#define N_EDGES 400000
#define F_NODE_ 64
#define F_EDGE_ 16
#define HID_ 128
#define N_GRAPH 1024
#define N_TASK 5
#define NSTRIPE 32

typedef unsigned short u16;
typedef __attribute__((ext_vector_type(8))) short frag8;   // 8 bf16 = 4 VGPRs
typedef __attribute__((ext_vector_type(4))) float f32x4;   // MFMA C/D
typedef __attribute__((ext_vector_type(2))) float f32x2;

__device__ __forceinline__ float bu2f(u16 v){ return __uint_as_float(((unsigned)v) << 16); }
__device__ __forceinline__ float2 bp2f(unsigned u){
  return make_float2(__uint_as_float(u << 16), __uint_as_float(u & 0xFFFF0000u));
}
__device__ __forceinline__ f32x2 bp2v(unsigned u){
  f32x2 r; r.x = __uint_as_float(u << 16); r.y = __uint_as_float(u & 0xFFFF0000u); return r;
}
__device__ __forceinline__ u16 f2bu(float f){
  __hip_bfloat16 h = __float2bfloat16(f);
  return *(u16*)&h;
}
__device__ __forceinline__ unsigned packbf(float a, float b){
  return (unsigned)f2bu(a) | ((unsigned)f2bu(b) << 16);
}
// packed 2-lane max (emits v_pk_max_f32 where available)
__device__ __forceinline__ f32x2 pmax2(f32x2 a, f32x2 b){
#if defined(__has_builtin)
#if __has_builtin(__builtin_elementwise_max)
  return __builtin_elementwise_max(a, b);
#else
  f32x2 r; r.x = fmaxf(a.x,b.x); r.y = fmaxf(a.y,b.y); return r;
#endif
#else
  f32x2 r; r.x = fmaxf(a.x,b.x); r.y = fmaxf(a.y,b.y); return r;
#endif
}

struct WZ12 { const float* src[12]; u16* dst[12]; int Ks[12]; int Kd[12]; };

// ---------------- cast f32->bf16 + edge histogram + graph offsets + W pre-swizzle (flat grid) ----------------
#define CAST_BLKS ((N_NODES*F_NODE_ + 255)/256)
#define EG256 ((N_EDGES + 255)/256)
#define GOFF_BLKS ((N_GRAPH + 1 + 255)/256)
#define WSWZ_BLKS (12*64)
__global__ __launch_bounds__(256) void k_cast_hist(const float* __restrict__ s, u16* __restrict__ d,
                                                   const int* __restrict__ ei, int* __restrict__ counts,
                                                   const int* __restrict__ batch, int* __restrict__ goff,
                                                   WZ12 p){
  int b = blockIdx.x;
  if (b < CAST_BLKS){
    int i = b*256 + threadIdx.x;
    if (i < N_NODES*F_NODE_) d[i] = f2bu(s[i]);
  } else if (b < CAST_BLKS + EG256){
    int e = (b - CAST_BLKS)*256 + threadIdx.x;
    if (e < N_EDGES) atomicAdd(&counts[ei[N_EDGES + e]], 1);
  } else if (b < CAST_BLKS + EG256 + GOFF_BLKS){
    int g = (b - CAST_BLKS - EG256)*256 + threadIdx.x;
    if (g <= N_GRAPH){
      int lo = 0, hi = N_NODES;
      while (lo < hi){
        int mid = (lo + hi) >> 1;
        if (batch[mid] < g) lo = mid + 1; else hi = mid;
      }
      goff[g] = lo;
    }
  } else {
    int bb = b - CAST_BLKS - EG256 - GOFF_BLKS;   // 0..767
    const int sW = bb >> 6;
    const int Kd = p.Kd[sW], Ks = p.Ks[sW];
    int i = (bb & 63)*256 + threadIdx.x;
    if (i >= Kd*128) return;
    int k = i >> 7, n = i & 127;
    float v = (k < Ks) ? p.src[sW][k*128 + n] : 0.f;
    int kk = k & 31, c = k >> 5;
    int quad = kk >> 3, j = kk & 7;
    int nt = n >> 4;
    int lane = quad*16 + (n & 15);
    p.dst[sW][(((c*8 + nt)*64) + lane)*8 + j] = f2bu(v);
  }
}

// ---------------- fused: paired MFMA GEMMs + eproj MFMA GEMM (flat grid) ----------------
// C-write: stage tile in LDS (quad-XOR swizzle, conflict-free) then coalesced uint4 stores.
#define GEMM_GRID ((N_NODES + 127)/128)   // 782
#define EPROJ_GRID ((N_EDGES + 127)/128)  // 3125
__global__ __launch_bounds__(256) void k_gemm_eproj(const u16* __restrict__ A,
                                                    const u16* __restrict__ Wzl,
                                                    const u16* __restrict__ Wzr,
                                                    const float* __restrict__ bl,
                                                    const float* __restrict__ br,
                                                    u16* __restrict__ Cl,
                                                    u16* Cr,
                                                    int M, int K,
                                                    const u16* __restrict__ ea16,
                                                    const u16* __restrict__ Wez,
                                                    u16* __restrict__ eproj){
  __shared__ u16 WS[128*128];
  const int t = threadIdx.x;
  const int b = blockIdx.x;
  if (b < 2*GEMM_GRID){
    const int which = (b >= GEMM_GRID);
    const int bx = which ? b - GEMM_GRID : b;
    const u16*   Wz   = which ? Wzr : Wzl;
    const float* bias = which ? br  : bl;
    u16*         C    = which ? Cr  : Cl;
    {
      const uint4* src = (const uint4*)Wz;
      uint4* dst = (uint4*)WS;
      const int n = (K*128) >> 3;
      for (int i = t; i < n; i += 256) dst[i] = src[i];
    }
    __syncthreads();
    const int w = t >> 6, l = t & 63;
    const int m = l & 15, quad = l >> 4;
    const int rowA0 = bx*128 + w*32 + m;
    const int rowA1 = rowA0 + 16;
    f32x4 acc[2][8];
    #pragma unroll
    for (int i=0;i<2;i++)
      #pragma unroll
      for (int j=0;j<8;j++) acc[i][j] = (f32x4){0.f,0.f,0.f,0.f};
    const int KC = K >> 5;
    for (int c = 0; c < KC; c++){
      frag8 a0 = {}, a1 = {};
      if (rowA0 < M) a0 = *(const frag8*)(A + (size_t)rowA0*K + c*32 + quad*8);
      if (rowA1 < M) a1 = *(const frag8*)(A + (size_t)rowA1*K + c*32 + quad*8);
      #pragma unroll
      for (int nt = 0; nt < 8; nt++){
        frag8 bfr = *(const frag8*)&WS[(((c*8 + nt)*64) + l)*8];
        acc[0][nt] = __builtin_amdgcn_mfma_f32_16x16x32_bf16(a0, bfr, acc[0][nt], 0,0,0);
        acc[1][nt] = __builtin_amdgcn_mfma_f32_16x16x32_bf16(a1, bfr, acc[1][nt], 0,0,0);
      }
    }
    float bcv[8];
    #pragma unroll
    for (int nt=0; nt<8; nt++) bcv[nt] = bias[nt*16 + m];
    __syncthreads();          // all WS reads (MFMA) done
    const int sXor = quad << 4;   // quads -> disjoint bank groups
    #pragma unroll
    for (int rt = 0; rt < 2; rt++){
      #pragma unroll
      for (int r = 0; r < 4; r++){
        const int row = w*32 + rt*16 + quad*4 + r;
        #pragma unroll
        for (int nt = 0; nt < 8; nt++){
          const int col = nt*16 + m;
          WS[row*128 + (col ^ sXor)] = f2bu(acc[rt][nt][r] + bcv[nt]);
        }
      }
    }
    __syncthreads();
    #pragma unroll
    for (int i = 0; i < 8; i++){
      const int idx = i*256 + t;
      const int row = idx >> 4, k16 = idx & 15;
      const int grp = (k16*8) ^ (((row>>2)&3)<<4);
      const int grow = bx*128 + row;
      if (grow < M)
        *(uint4*)(C + (size_t)grow*128 + k16*8) = *(const uint4*)&WS[row*128 + grp];
    }
  } else {
    // eproj GEMM: 128 edges/block, K=32 via fragment zero-padding
    const int bx = b - 2*GEMM_GRID;
    {
      const uint4* s4 = (const uint4*)Wez;
      uint4* d4 = (uint4*)WS;
      for (int i = t; i < 512; i += 256) d4[i] = s4[i];
    }
    __syncthreads();
    const int w = t >> 6, l = t & 63, m = l & 15, quad = l >> 4;
    const int row0 = bx*128 + w*32 + m;
    const int row1 = row0 + 16;
    f32x4 acc[2][8];
    #pragma unroll
    for (int i=0;i<2;i++)
      #pragma unroll
      for (int j=0;j<8;j++) acc[i][j] = (f32x4){0.f,0.f,0.f,0.f};
    frag8 a0 = {}, a1 = {};
    if (quad < 2){
      a0 = *(const frag8*)(ea16 + (size_t)row0*16 + quad*8);   // grid exact: rows < N_EDGES
      a1 = *(const frag8*)(ea16 + (size_t)row1*16 + quad*8);
    }
    #pragma unroll
    for (int nt = 0; nt < 8; nt++){
      frag8 bfr = *(const frag8*)&WS[(nt*64 + l)*8];
      acc[0][nt] = __builtin_amdgcn_mfma_f32_16x16x32_bf16(a0, bfr, acc[0][nt], 0,0,0);
      acc[1][nt] = __builtin_amdgcn_mfma_f32_16x16x32_bf16(a1, bfr, acc[1][nt], 0,0,0);
    }
    __syncthreads();
    const int sXor = quad << 4;
    #pragma unroll
    for (int rt = 0; rt < 2; rt++){
      #pragma unroll
      for (int r = 0; r < 4; r++){
        const int row = w*32 + rt*16 + quad*4 + r;
        #pragma unroll
        for (int nt = 0; nt < 8; nt++){
          const int col = nt*16 + m;
          WS[row*128 + (col ^ sXor)] = f2bu(acc[rt][nt][r]);
        }
      }
    }
    __syncthreads();
    #pragma unroll
    for (int i = 0; i < 8; i++){
      const int idx = i*256 + t;
      const int row = idx >> 4, k16 = idx & 15;
      const int grp = (k16*8) ^ (((row>>2)&3)<<4);
      *(uint4*)(eproj + ((size_t)(bx*128 + row))*128 + k16*8) = *(const uint4*)&WS[row*128 + grp];
    }
  }
}

__global__ __launch_bounds__(512) void k_scan1(const int* __restrict__ counts,
                                               int* __restrict__ incl,
                                               int* __restrict__ bsum){
  __shared__ int s[512];
  const int t = threadIdx.x;
  int i = blockIdx.x*512 + t;
  int v = (i < N_NODES) ? counts[i] : 0;
  s[t] = v;
  __syncthreads();
  for (int off = 1; off < 512; off <<= 1){
    int x = (t >= off) ? s[t - off] : 0;
    __syncthreads();
    s[t] += x;
    __syncthreads();
  }
  if (i < N_NODES) incl[i] = s[t];
  if (t == 511) bsum[blockIdx.x] = s[511];
}

// scan3 with in-block redundant scan of bsum
__global__ __launch_bounds__(512) void k_scan3(const int* __restrict__ counts,
                                               const int* __restrict__ incl,
                                               const int* __restrict__ bsum, int nb,
                                               int* __restrict__ offsets,
                                               int* __restrict__ cursor){
  __shared__ int sb[256];
  const int t = threadIdx.x;
  if (t < 256) sb[t] = (t < nb) ? bsum[t] : 0;
  __syncthreads();
  for (int off = 1; off < 256; off <<= 1){
    int x = 0;
    if (t < 256 && t >= off) x = sb[t - off];
    __syncthreads();
    if (t < 256) sb[t] += x;
    __syncthreads();
  }
  int i = blockIdx.x*512 + t;
  if (i >= N_NODES) return;
  int pre = (blockIdx.x == 0) ? 0 : sb[blockIdx.x - 1];
  int o = pre + incl[i];
  offsets[i + 1] = o;
  cursor[i]      = o - counts[i];
  if (i == 0) offsets[0] = 0;
}

// scatter: src index + bf16 edge features into CSR order ([E][16] bf16)
__global__ __launch_bounds__(256) void k_scatter(const int* __restrict__ ei,
                                                 int* __restrict__ cursor,
                                                 int* __restrict__ ssrc,
                                                 const float* __restrict__ ea,
                                                 u16* __restrict__ ea16){
  int e = blockIdx.x*256 + threadIdx.x;
  if (e >= N_EDGES) return;
  int dst = ei[N_EDGES + e];
  int pos = atomicAdd(&cursor[dst], 1);
  ssrc[pos] = ei[e];
  const float* s = ea + (size_t)e*F_EDGE_;
  unsigned p[8];
  #pragma unroll
  for (int k=0;k<8;k++) p[k] = packbf(s[2*k], s[2*k+1]);
  uint4* d4 = (uint4*)(ea16 + (size_t)pos*16);
  d4[0] = make_uint4(p[0],p[1],p[2],p[3]);
  d4[1] = make_uint4(p[4],p[5],p[6],p[7]);
}

// ---------------- Fused GAT v19: 2 nodes/wave, 8 edges/iter (deep ILP), BN-stats tail (32-way stripe) ----------------
#define GAT_GRID (N_NODES/8)   // 12500 blocks of 128 threads
__global__ __launch_bounds__(128) void k_gat_ep(const u16* __restrict__ xl,
                                                unsigned* xr_aggr,
                                                const u16* __restrict__ eproj,
                                                const float* __restrict__ att,
                                                const int* __restrict__ offsets,
                                                const int* __restrict__ ssrc,
                                                float* __restrict__ stats){
  __shared__ float red[4][264];           // [group][0..127 sum | 128..255 sq]
  const int t = threadIdx.x;              // 0..127
  const int wave = t >> 6, lane = t & 63;
  const int half = lane >> 5, l32 = lane & 31;
  const int c0 = l32*4;                   // 4 channels per lane
  const float4 av = *(const float4*)(att + c0);
  const f32x2 avlo = {av.x, av.y}, avhi = {av.z, av.w};
  float ss0=0.f, ss1=0.f, ss2=0.f, ss3=0.f;
  float qq0=0.f, qq1=0.f, qq2=0.f, qq3=0.f;

  for (int k = 0; k < 2; k++){
    const int node = blockIdx.x*8 + wave*4 + k*2 + half;    // < N_NODES (grid exact)
    const uint2 xru = *(const uint2*)(xr_aggr + (size_t)node*64 + l32*2);
    const f32x2 xr0 = bp2v(xru.x), xr1 = bp2v(xru.y);
    f32x2 acc0 = {0.f,0.f}, acc1 = {0.f,0.f};
    float den = 0.f;
    const int beg = offsets[node], end = offsets[node+1];
    int it = (end - beg + 7) >> 3;
    int oit = __shfl_xor(it, 32);
    const int maxit = it > oit ? it : oit;
    int i = beg;
    for (int n = 0; n < maxit; n++, i += 8){
      const int mm = end - i;                 // may be <= 0 for exhausted half
      int ib = (mm > 0) ? i : beg;
      ib = ib < N_EDGES ? ib : N_EDGES - 1;
      int idx[8];
      #pragma unroll
      for (int j = 0; j < 8; j++) idx[j] = (mm > j) ? i + j : ib;
      int sIdx[8];
      #pragma unroll
      for (int j = 0; j < 8; j++) sIdx[j] = ssrc[idx[j]];
      uint2 ev[8], xv[8];
      #pragma unroll
      for (int j = 0; j < 8; j++) ev[j] = *(const uint2*)(eproj + (size_t)idx[j]*128 + c0);
      #pragma unroll
      for (int j = 0; j < 8; j++) xv[j] = *(const uint2*)(xl + (size_t)sIdx[j]*HID_ + c0);
      f32x2 vl0[8], vl1[8];
      float sc[8];
      #pragma unroll
      for (int j = 0; j < 8; j++){
        vl0[j] = bp2v(xv[j].x); vl1[j] = bp2v(xv[j].y);
        f32x2 v0 = vl0[j] + xr0 + bp2v(ev[j].x);
        f32x2 v1 = vl1[j] + xr1 + bp2v(ev[j].y);
        v0 = pmax2(v0, v0*0.2f);
        v1 = pmax2(v1, v1*0.2f);
        f32x2 ps = v0*avlo + v1*avhi;
        sc[j] = ps.x + ps.y;
      }
      #pragma unroll
      for (int j = 0; j < 8; j++) sc[j] += __shfl_xor(sc[j], 1);
      #pragma unroll
      for (int j = 0; j < 8; j++) sc[j] += __shfl_xor(sc[j], 2);
      #pragma unroll
      for (int j = 0; j < 8; j++) sc[j] += __shfl_xor(sc[j], 4);
      #pragma unroll
      for (int j = 0; j < 8; j++){
        const float p = (mm > j) ? __expf(sc[j]) : 0.f;
        acc0 += p*vl0[j];
        acc1 += p*vl1[j];
        den  += p;
      }
    }
    const float inv = 1.0f / (den + 1e-16f);
    uint2 outv;
    outv.x = packbf(acc0.x*inv, acc0.y*inv);
    outv.y = packbf(acc1.x*inv, acc1.y*inv);
    *(uint2*)(xr_aggr + (size_t)node*64 + l32*2) = outv;
    const float2 o0 = bp2f(outv.x), o1 = bp2f(outv.y);
    ss0 += o0.x; ss1 += o0.y; ss2 += o1.x; ss3 += o1.y;
    qq0 += o0.x*o0.x; qq1 += o0.y*o0.y; qq2 += o1.x*o1.x; qq3 += o1.y*o1.y;
  }
  const int g = wave*2 + half;            // 0..3
  red[g][c0+0] = ss0; red[g][c0+1] = ss1; red[g][c0+2] = ss2; red[g][c0+3] = ss3;
  red[g][128+c0+0] = qq0; red[g][128+c0+1] = qq1; red[g][128+c0+2] = qq2; red[g][128+c0+3] = qq3;
  __syncthreads();
  {
    float a = 0.f, b2 = 0.f;
    #pragma unroll
    for (int gg = 0; gg < 4; gg++){ a += red[gg][t]; b2 += red[gg][128+t]; }
    const int base = (blockIdx.x & (NSTRIPE-1))*256;   // 32-way stripe
    atomicAdd(&stats[base + t],       a);
    atomicAdd(&stats[base + 128 + t], b2);
  }
}

// ---------------- BN apply + ELU (+ residual): pre-reduce 32 stripes + scale/shift in LDS ----------------
__global__ __launch_bounds__(256) void k_bn_apply(const unsigned* __restrict__ aggr_b,
                                                  const float* __restrict__ stats,
                                                  const float* __restrict__ gamma,
                                                  const float* __restrict__ beta,
                                                  u16* __restrict__ h, int residual){
  __shared__ float sc_sh[128], sh_sh[128];
  const int t = threadIdx.x;
  if (t < 128){
    float s = 0.f, q = 0.f;
    #pragma unroll
    for (int st = 0; st < NSTRIPE; st++){
      s += stats[st*256 + t];
      q += stats[st*256 + 128 + t];
    }
    const float invn = 1.0f / (float)N_NODES;
    float mu = s * invn;
    float var = q * invn - mu*mu;
    float sc = rsqrtf(var + 1e-5f) * gamma[t];
    sc_sh[t] = sc;
    sh_sh[t] = beta[t] - mu * sc;
  }
  __syncthreads();
  size_t i = (size_t)blockIdx.x*256 + t;   // uint4-group index (8 channels)
  if (i >= (size_t)N_NODES*16) return;
  const int c = (int)((i & 15) * 8);
  uint4 v4 = ((const uint4*)aggr_b)[i];
  uint4* hp = (uint4*)h + i;
  uint4 hv4 = make_uint4(0,0,0,0);
  if (residual) hv4 = *hp;
  unsigned vin[4]  = {v4.x, v4.y, v4.z, v4.w};
  unsigned hin[4]  = {hv4.x, hv4.y, hv4.z, hv4.w};
  unsigned outw[4];
  #pragma unroll
  for (int j=0;j<4;j++){
    int cc = c + j*2;
    float2 v = bp2f(vin[j]);
    float val0 = v.x * sc_sh[cc]   + sh_sh[cc];
    float val1 = v.y * sc_sh[cc+1] + sh_sh[cc+1];
    val0 = val0 > 0.f ? val0 : expm1f(val0);
    val1 = val1 > 0.f ? val1 : expm1f(val1);
    if (residual){
      float2 hv = bp2f(hin[j]);
      val0 += hv.x; val1 += hv.y;
    }
    outw[j] = packbf(val0, val1);
  }
  *hp = make_uint4(outw[0], outw[1], outw[2], outw[3]);
}

// ---------------- Pool: segmented mean (1024 blocks) ----------------
__global__ __launch_bounds__(256) void k_pool_seg(const unsigned* __restrict__ h2,
                                                  const int* __restrict__ goff,
                                                  float* __restrict__ emb){
  __shared__ float redS[4][128];
  const int g = blockIdx.x, t = threadIdx.x;
  const int p = t & 63, rg = t >> 6;
  const int beg = goff[g], end = goff[g+1];
  float a0 = 0.f, a1 = 0.f;
  for (int r = beg + rg; r < end; r += 4){
    float2 v = bp2f(h2[(size_t)r*64 + p]);
    a0 += v.x; a1 += v.y;
  }
  redS[rg][p*2] = a0; redS[rg][p*2+1] = a1;
  __syncthreads();
  if (rg == 0){
    #pragma unroll
    for (int k=1;k<4;k++){ a0 += redS[k][p*2]; a1 += redS[k][p*2+1]; }
    float n = fmaxf((float)(end - beg), 1.f);
    emb[(size_t)g*HID_ + p*2]     = a0 / n;
    emb[(size_t)g*HID_ + p*2 + 1] = a1 / n;
  }
}

// ---------------- Per-task heads: 8 graphs per block, (128,5) grid ----------------
#define HG 8
__global__ __launch_bounds__(128) void k_heads(const float* __restrict__ emb,
                                               const float* __restrict__ mf,
                                               const int* __restrict__ fpi,
                                               const float* __restrict__ tw1,
                                               const float* __restrict__ tb1,
                                               const float* __restrict__ tw2,
                                               const float* __restrict__ tb2,
                                               float* __restrict__ out){
  const int task = blockIdx.y, g0 = blockIdx.x*HG;
  const int j = threadIdx.x;
  __shared__ float fused[HG][160];
  __shared__ float red[HG][128];
  for (int idx = j; idx < HG*160; idx += 128){
    int g = idx / 160, i = idx % 160;
    float v;
    if (i < 128) v = emb[(size_t)(g0+g)*HID_ + i];
    else         v = mf[(size_t)(g0+g)*2048 + fpi[task*32 + (i-128)]];
    fused[g][i] = v;
  }
  __syncthreads();
  const float* w1 = tw1 + (size_t)task*160*128;
  float acc[HG];
  float b1 = tb1[task*128 + j];
  #pragma unroll
  for (int g=0; g<HG; g++) acc[g] = b1;
  for (int i=0; i<160; i++){
    float wv = w1[(size_t)i*128 + j];
    #pragma unroll
    for (int g=0; g<HG; g++) acc[g] += fused[g][i] * wv;
  }
  float t2 = tw2[task*128 + j];
  #pragma unroll
  for (int g=0; g<HG; g++){
    float v = acc[g] > 0.f ? acc[g] : 0.f;
    red[g][j] = v * t2;
  }
  __syncthreads();
  int g = j >> 4, l16 = j & 15;
  float s = 0.f;
  #pragma unroll
  for (int k=0;k<8;k++) s += red[g][l16 + k*16];
  s += __shfl_xor(s, 1, 16);
  s += __shfl_xor(s, 2, 16);
  s += __shfl_xor(s, 4, 16);
  s += __shfl_xor(s, 8, 16);
  if (l16 == 0) out[(size_t)(g0+g)*N_TASK + task] = s + tb2[task];
}

extern "C" void kernel_launch(void* const* d_in, const int* in_sizes, int n_in,
                              void* d_out, int out_size, void* d_ws, size_t ws_size,
                              hipStream_t stream){
  const float* x    = (const float*)d_in[0];
  const int*   ei   = (const int*)  d_in[1];
  const float* ea   = (const float*)d_in[2];
  const int*   batch= (const int*)  d_in[3];
  const float* mf   = (const float*)d_in[4];
  const int*   fpi  = (const int*)  d_in[5];
  const float* Wl0  = (const float*)d_in[6];
  const float* bl0  = (const float*)d_in[7];
  const float* Wr0  = (const float*)d_in[8];
  const float* br0  = (const float*)d_in[9];
  const float* We0  = (const float*)d_in[10];
  const float* att0 = (const float*)d_in[11];
  const float* g0   = (const float*)d_in[13];
  const float* b0   = (const float*)d_in[14];
  const float* Wl   = (const float*)d_in[15];
  const float* bl   = (const float*)d_in[16];
  const float* Wr   = (const float*)d_in[17];
  const float* br   = (const float*)d_in[18];
  const float* We   = (const float*)d_in[19];
  const float* att  = (const float*)d_in[20];
  const float* gg   = (const float*)d_in[22];
  const float* bb   = (const float*)d_in[23];
  const float* tw1  = (const float*)d_in[24];
  const float* tb1  = (const float*)d_in[25];
  const float* tw2  = (const float*)d_in[26];
  const float* tb2  = (const float*)d_in[27];
  float* out = (float*)d_out;

  char* w = (char*)d_ws;
  auto alloc = [&](size_t bytes)->char*{ char* r = w; w += (bytes + 255) & ~(size_t)255; return r; };
  u16*   xl     = (u16*)  alloc((size_t)N_NODES*HID_*2);
  unsigned* xr_aggr = (unsigned*)alloc((size_t)N_NODES*64*4);
  u16*   h      = (u16*)  alloc((size_t)N_NODES*HID_*2);
  u16*   ea16   = (u16*)  alloc((size_t)N_EDGES*16*2);
  int*   counts = (int*)  alloc((size_t)N_NODES*4);
  float* stats4 = (float*)alloc(4*NSTRIPE*256*4);      // 4 layers x 32 stripes x 256 floats
  int*   offsets= (int*)  alloc((size_t)(N_NODES+1)*4);
  int*   cursor = (int*)  alloc((size_t)N_NODES*4);
  int*   incl   = (int*)  alloc((size_t)N_NODES*4);
  int*   bsum   = (int*)  alloc(256*4);
  int*   ssrc   = (int*)  alloc((size_t)N_EDGES*4);
  int*   goff   = (int*)  alloc((size_t)(N_GRAPH+1)*4);
  float* emb    = (float*)alloc((size_t)N_GRAPH*HID_*4);
  u16*   Wzl0   = (u16*)  alloc((size_t)F_NODE_*128*2);
  u16*   Wzr0   = (u16*)  alloc((size_t)F_NODE_*128*2);
  u16*   Wzl123 = (u16*)  alloc((size_t)3*HID_*128*2);
  u16*   Wzr123 = (u16*)  alloc((size_t)3*HID_*128*2);
  u16*   Wez4   = (u16*)  alloc((size_t)4*32*128*2);
  u16*   eproj  = (u16*)  alloc((size_t)N_EDGES*HID_*2);
  u16*   xbf    = (u16*)  alloc((size_t)N_NODES*F_NODE_*2);  // separate from eproj (no race)

  const size_t zlen = (size_t)((char*)(stats4 + 4*NSTRIPE*256) - (char*)counts);
  const int nscan = (N_NODES + 511)/512;

  WZ12 p;
  p.src[0] = Wl0; p.dst[0] = Wzl0; p.Ks[0] = F_NODE_; p.Kd[0] = F_NODE_;
  p.src[1] = Wr0; p.dst[1] = Wzr0; p.Ks[1] = F_NODE_; p.Kd[1] = F_NODE_;
  for (int i=0;i<3;i++){
    p.src[2+i] = Wl + (size_t)i*HID_*HID_; p.dst[2+i] = Wzl123 + (size_t)i*HID_*128; p.Ks[2+i] = HID_; p.Kd[2+i] = HID_;
    p.src[5+i] = Wr + (size_t)i*HID_*HID_; p.dst[5+i] = Wzr123 + (size_t)i*HID_*128; p.Ks[5+i] = HID_; p.Kd[5+i] = HID_;
  }
  p.src[8] = We0; p.dst[8] = Wez4; p.Ks[8] = F_EDGE_; p.Kd[8] = 32;
  for (int i=0;i<3;i++){
    p.src[9+i] = We + (size_t)i*F_EDGE_*HID_; p.dst[9+i] = Wez4 + (size_t)(i+1)*32*128; p.Ks[9+i] = F_EDGE_; p.Kd[9+i] = 32;
  }

  hipMemsetAsync(counts, 0, zlen, stream);
  hipLaunchKernelGGL(k_cast_hist, dim3(CAST_BLKS + EG256 + GOFF_BLKS + WSWZ_BLKS), dim3(256), 0, stream,
                     x, xbf, ei, counts, batch, goff, p);
  hipLaunchKernelGGL(k_scan1,  dim3(nscan), dim3(512), 0, stream, counts, incl, bsum);
  hipLaunchKernelGGL(k_scan3,  dim3(nscan), dim3(512), 0, stream, counts, incl, bsum, nscan, offsets, cursor);
  hipLaunchKernelGGL(k_scatter,dim3(EG256), dim3(256), 0, stream, ei, cursor, ssrc, ea, ea16);

  for (int layer = 0; layer < 4; layer++){
    const float *bl_, *br_, *att_, *g_, *b_;
    const u16 *Wzl_, *Wzr_, *Ain;
    int K;
    if (layer == 0){
      bl_=bl0; br_=br0; att_=att0; g_=g0; b_=b0;
      Wzl_ = Wzl0; Wzr_ = Wzr0; Ain = xbf; K = F_NODE_;
    } else {
      int i = layer - 1;
      bl_ = bl + (size_t)i*HID_;  br_ = br + (size_t)i*HID_;
      att_= att + (size_t)i*HID_;
      g_  = gg + (size_t)i*HID_;  b_  = bb + (size_t)i*HID_;
      Wzl_ = Wzl123 + (size_t)i*HID_*128;
      Wzr_ = Wzr123 + (size_t)i*HID_*128;
      Ain = h; K = HID_;
    }
    float* stats = stats4 + (size_t)layer*NSTRIPE*256;
    hipLaunchKernelGGL(k_gemm_eproj, dim3(2*GEMM_GRID + EPROJ_GRID), dim3(256), 0, stream,
                       Ain, Wzl_, Wzr_, bl_, br_, xl, (u16*)xr_aggr, N_NODES, K,
                       ea16, Wez4 + (size_t)layer*32*128, eproj);
    hipLaunchKernelGGL(k_gat_ep, dim3(GAT_GRID), dim3(128), 0, stream,
                       xl, xr_aggr, eproj, att_, offsets, ssrc, stats);
    hipLaunchKernelGGL(k_bn_apply, dim3((N_NODES*16 + 255)/256), dim3(256), 0, stream,
                       xr_aggr, stats, g_, b_, h, layer > 0 ? 1 : 0);
  }
  hipLaunchKernelGGL(k_pool_seg, dim3(N_GRAPH), dim3(256), 0, stream, (const unsigned*)h, goff, emb);
  hipLaunchKernelGGL(k_heads, dim3(N_GRAPH/HG, N_TASK), dim3(128), 0, stream, emb, mf, fpi, tw1, tb1, tw2, tb2, out);
}

// Round 14
// 642.618 us; speedup vs baseline: 1.0434x; 1.0434x over previous
//
#include <hip/hip_runtime.h>
#include <hip/hip_bf16.h>

#define N_NODES 100000
#define N_EDGES 400000
#define F_NODE_ 64
#define F_EDGE_ 16
#define HID_ 128
#define N_GRAPH 1024
#define N_TASK 5
#define NSTRIPE 32

typedef unsigned short u16;
typedef __attribute__((ext_vector_type(8))) short frag8;   // 8 bf16 = 4 VGPRs
typedef __attribute__((ext_vector_type(4))) float f32x4;   // MFMA C/D
typedef __attribute__((ext_vector_type(2))) float f32x2;

__device__ __forceinline__ float bu2f(u16 v){ return __uint_as_float(((unsigned)v) << 16); }
__device__ __forceinline__ float2 bp2f(unsigned u){
  return make_float2(__uint_as_float(u << 16), __uint_as_float(u & 0xFFFF0000u));
}
__device__ __forceinline__ f32x2 bp2v(unsigned u){
  f32x2 r; r.x = __uint_as_float(u << 16); r.y = __uint_as_float(u & 0xFFFF0000u); return r;
}
__device__ __forceinline__ u16 f2bu(float f){
  __hip_bfloat16 h = __float2bfloat16(f);
  return *(u16*)&h;
}
__device__ __forceinline__ unsigned packbf(float a, float b){
  return (unsigned)f2bu(a) | ((unsigned)f2bu(b) << 16);
}
// packed 2-lane max (emits v_pk_max_f32 where available)
__device__ __forceinline__ f32x2 pmax2(f32x2 a, f32x2 b){
#if defined(__has_builtin)
#if __has_builtin(__builtin_elementwise_max)
  return __builtin_elementwise_max(a, b);
#else
  f32x2 r; r.x = fmaxf(a.x,b.x); r.y = fmaxf(a.y,b.y); return r;
#endif
#else
  f32x2 r; r.x = fmaxf(a.x,b.x); r.y = fmaxf(a.y,b.y); return r;
#endif
}

struct WZ12 { const float* src[12]; u16* dst[12]; int Ks[12]; int Kd[12]; };

// ---------------- cast f32->bf16 + edge histogram + graph offsets + W pre-swizzle (flat grid) ----------------
#define CAST_BLKS ((N_NODES*F_NODE_ + 255)/256)
#define EG256 ((N_EDGES + 255)/256)
#define GOFF_BLKS ((N_GRAPH + 1 + 255)/256)
#define WSWZ_BLKS (12*64)
__global__ __launch_bounds__(256) void k_cast_hist(const float* __restrict__ s, u16* __restrict__ d,
                                                   const int* __restrict__ ei, int* __restrict__ counts,
                                                   const int* __restrict__ batch, int* __restrict__ goff,
                                                   WZ12 p){
  int b = blockIdx.x;
  if (b < CAST_BLKS){
    int i = b*256 + threadIdx.x;
    if (i < N_NODES*F_NODE_) d[i] = f2bu(s[i]);
  } else if (b < CAST_BLKS + EG256){
    int e = (b - CAST_BLKS)*256 + threadIdx.x;
    if (e < N_EDGES) atomicAdd(&counts[ei[N_EDGES + e]], 1);
  } else if (b < CAST_BLKS + EG256 + GOFF_BLKS){
    int g = (b - CAST_BLKS - EG256)*256 + threadIdx.x;
    if (g <= N_GRAPH){
      int lo = 0, hi = N_NODES;
      while (lo < hi){
        int mid = (lo + hi) >> 1;
        if (batch[mid] < g) lo = mid + 1; else hi = mid;
      }
      goff[g] = lo;
    }
  } else {
    int bb = b - CAST_BLKS - EG256 - GOFF_BLKS;   // 0..767
    const int sW = bb >> 6;
    const int Kd = p.Kd[sW], Ks = p.Ks[sW];
    int i = (bb & 63)*256 + threadIdx.x;
    if (i >= Kd*128) return;
    int k = i >> 7, n = i & 127;
    float v = (k < Ks) ? p.src[sW][k*128 + n] : 0.f;
    int kk = k & 31, c = k >> 5;
    int quad = kk >> 3, j = kk & 7;
    int nt = n >> 4;
    int lane = quad*16 + (n & 15);
    p.dst[sW][(((c*8 + nt)*64) + lane)*8 + j] = f2bu(v);
  }
}

// ---------------- fused: paired MFMA GEMMs + eproj MFMA GEMM (flat grid) ----------------
// C-write: stage tile in LDS (quad-XOR swizzle, conflict-free) then coalesced uint4 stores.
#define GEMM_GRID ((N_NODES + 127)/128)   // 782
#define EPROJ_GRID ((N_EDGES + 127)/128)  // 3125
__global__ __launch_bounds__(256) void k_gemm_eproj(const u16* __restrict__ A,
                                                    const u16* __restrict__ Wzl,
                                                    const u16* __restrict__ Wzr,
                                                    const float* __restrict__ bl,
                                                    const float* __restrict__ br,
                                                    u16* __restrict__ Cl,
                                                    u16* Cr,
                                                    int M, int K,
                                                    const u16* __restrict__ ea16,
                                                    const u16* __restrict__ Wez,
                                                    u16* __restrict__ eproj){
  __shared__ u16 WS[128*128];
  const int t = threadIdx.x;
  const int b = blockIdx.x;
  if (b < 2*GEMM_GRID){
    const int which = (b >= GEMM_GRID);
    const int bx = which ? b - GEMM_GRID : b;
    const u16*   Wz   = which ? Wzr : Wzl;
    const float* bias = which ? br  : bl;
    u16*         C    = which ? Cr  : Cl;
    {
      const uint4* src = (const uint4*)Wz;
      uint4* dst = (uint4*)WS;
      const int n = (K*128) >> 3;
      for (int i = t; i < n; i += 256) dst[i] = src[i];
    }
    __syncthreads();
    const int w = t >> 6, l = t & 63;
    const int m = l & 15, quad = l >> 4;
    const int rowA0 = bx*128 + w*32 + m;
    const int rowA1 = rowA0 + 16;
    f32x4 acc[2][8];
    #pragma unroll
    for (int i=0;i<2;i++)
      #pragma unroll
      for (int j=0;j<8;j++) acc[i][j] = (f32x4){0.f,0.f,0.f,0.f};
    const int KC = K >> 5;
    for (int c = 0; c < KC; c++){
      frag8 a0 = {}, a1 = {};
      if (rowA0 < M) a0 = *(const frag8*)(A + (size_t)rowA0*K + c*32 + quad*8);
      if (rowA1 < M) a1 = *(const frag8*)(A + (size_t)rowA1*K + c*32 + quad*8);
      #pragma unroll
      for (int nt = 0; nt < 8; nt++){
        frag8 bfr = *(const frag8*)&WS[(((c*8 + nt)*64) + l)*8];
        acc[0][nt] = __builtin_amdgcn_mfma_f32_16x16x32_bf16(a0, bfr, acc[0][nt], 0,0,0);
        acc[1][nt] = __builtin_amdgcn_mfma_f32_16x16x32_bf16(a1, bfr, acc[1][nt], 0,0,0);
      }
    }
    float bcv[8];
    #pragma unroll
    for (int nt=0; nt<8; nt++) bcv[nt] = bias[nt*16 + m];
    __syncthreads();          // all WS reads (MFMA) done
    const int sXor = quad << 4;   // quads -> disjoint bank groups
    #pragma unroll
    for (int rt = 0; rt < 2; rt++){
      #pragma unroll
      for (int r = 0; r < 4; r++){
        const int row = w*32 + rt*16 + quad*4 + r;
        #pragma unroll
        for (int nt = 0; nt < 8; nt++){
          const int col = nt*16 + m;
          WS[row*128 + (col ^ sXor)] = f2bu(acc[rt][nt][r] + bcv[nt]);
        }
      }
    }
    __syncthreads();
    #pragma unroll
    for (int i = 0; i < 8; i++){
      const int idx = i*256 + t;
      const int row = idx >> 4, k16 = idx & 15;
      const int grp = (k16*8) ^ (((row>>2)&3)<<4);
      const int grow = bx*128 + row;
      if (grow < M)
        *(uint4*)(C + (size_t)grow*128 + k16*8) = *(const uint4*)&WS[row*128 + grp];
    }
  } else {
    // eproj GEMM: 128 edges/block, K=32 via fragment zero-padding
    const int bx = b - 2*GEMM_GRID;
    {
      const uint4* s4 = (const uint4*)Wez;
      uint4* d4 = (uint4*)WS;
      for (int i = t; i < 512; i += 256) d4[i] = s4[i];
    }
    __syncthreads();
    const int w = t >> 6, l = t & 63, m = l & 15, quad = l >> 4;
    const int row0 = bx*128 + w*32 + m;
    const int row1 = row0 + 16;
    f32x4 acc[2][8];
    #pragma unroll
    for (int i=0;i<2;i++)
      #pragma unroll
      for (int j=0;j<8;j++) acc[i][j] = (f32x4){0.f,0.f,0.f,0.f};
    frag8 a0 = {}, a1 = {};
    if (quad < 2){
      a0 = *(const frag8*)(ea16 + (size_t)row0*16 + quad*8);   // grid exact: rows < N_EDGES
      a1 = *(const frag8*)(ea16 + (size_t)row1*16 + quad*8);
    }
    #pragma unroll
    for (int nt = 0; nt < 8; nt++){
      frag8 bfr = *(const frag8*)&WS[(nt*64 + l)*8];
      acc[0][nt] = __builtin_amdgcn_mfma_f32_16x16x32_bf16(a0, bfr, acc[0][nt], 0,0,0);
      acc[1][nt] = __builtin_amdgcn_mfma_f32_16x16x32_bf16(a1, bfr, acc[1][nt], 0,0,0);
    }
    __syncthreads();
    const int sXor = quad << 4;
    #pragma unroll
    for (int rt = 0; rt < 2; rt++){
      #pragma unroll
      for (int r = 0; r < 4; r++){
        const int row = w*32 + rt*16 + quad*4 + r;
        #pragma unroll
        for (int nt = 0; nt < 8; nt++){
          const int col = nt*16 + m;
          WS[row*128 + (col ^ sXor)] = f2bu(acc[rt][nt][r]);
        }
      }
    }
    __syncthreads();
    #pragma unroll
    for (int i = 0; i < 8; i++){
      const int idx = i*256 + t;
      const int row = idx >> 4, k16 = idx & 15;
      const int grp = (k16*8) ^ (((row>>2)&3)<<4);
      *(uint4*)(eproj + ((size_t)(bx*128 + row))*128 + k16*8) = *(const uint4*)&WS[row*128 + grp];
    }
  }
}

__global__ __launch_bounds__(512) void k_scan1(const int* __restrict__ counts,
                                               int* __restrict__ incl,
                                               int* __restrict__ bsum){
  __shared__ int s[512];
  const int t = threadIdx.x;
  int i = blockIdx.x*512 + t;
  int v = (i < N_NODES) ? counts[i] : 0;
  s[t] = v;
  __syncthreads();
  for (int off = 1; off < 512; off <<= 1){
    int x = (t >= off) ? s[t - off] : 0;
    __syncthreads();
    s[t] += x;
    __syncthreads();
  }
  if (i < N_NODES) incl[i] = s[t];
  if (t == 511) bsum[blockIdx.x] = s[511];
}

// scan3 with in-block redundant scan of bsum
__global__ __launch_bounds__(512) void k_scan3(const int* __restrict__ counts,
                                               const int* __restrict__ incl,
                                               const int* __restrict__ bsum, int nb,
                                               int* __restrict__ offsets,
                                               int* __restrict__ cursor){
  __shared__ int sb[256];
  const int t = threadIdx.x;
  if (t < 256) sb[t] = (t < nb) ? bsum[t] : 0;
  __syncthreads();
  for (int off = 1; off < 256; off <<= 1){
    int x = 0;
    if (t < 256 && t >= off) x = sb[t - off];
    __syncthreads();
    if (t < 256) sb[t] += x;
    __syncthreads();
  }
  int i = blockIdx.x*512 + t;
  if (i >= N_NODES) return;
  int pre = (blockIdx.x == 0) ? 0 : sb[blockIdx.x - 1];
  int o = pre + incl[i];
  offsets[i + 1] = o;
  cursor[i]      = o - counts[i];
  if (i == 0) offsets[0] = 0;
}

// scatter: src index + bf16 edge features into CSR order ([E][16] bf16)
__global__ __launch_bounds__(256) void k_scatter(const int* __restrict__ ei,
                                                 int* __restrict__ cursor,
                                                 int* __restrict__ ssrc,
                                                 const float* __restrict__ ea,
                                                 u16* __restrict__ ea16){
  int e = blockIdx.x*256 + threadIdx.x;
  if (e >= N_EDGES) return;
  int dst = ei[N_EDGES + e];
  int pos = atomicAdd(&cursor[dst], 1);
  ssrc[pos] = ei[e];
  const float* s = ea + (size_t)e*F_EDGE_;
  unsigned p[8];
  #pragma unroll
  for (int k=0;k<8;k++) p[k] = packbf(s[2*k], s[2*k+1]);
  uint4* d4 = (uint4*)(ea16 + (size_t)pos*16);
  d4[0] = make_uint4(p[0],p[1],p[2],p[3]);
  d4[1] = make_uint4(p[4],p[5],p[6],p[7]);
}

// ---------------- Fused GAT v18: 2 nodes/wave, 128-thr blocks, BN-stats tail (32-way stripe) ----------------
#define GAT_GRID (N_NODES/8)   // 12500 blocks of 128 threads
__global__ __launch_bounds__(128) void k_gat_ep(const u16* __restrict__ xl,
                                                unsigned* xr_aggr,
                                                const u16* __restrict__ eproj,
                                                const float* __restrict__ att,
                                                const int* __restrict__ offsets,
                                                const int* __restrict__ ssrc,
                                                float* __restrict__ stats){
  __shared__ float red[4][264];           // [group][0..127 sum | 128..255 sq]
  const int t = threadIdx.x;              // 0..127
  const int wave = t >> 6, lane = t & 63;
  const int half = lane >> 5, l32 = lane & 31;
  const int c0 = l32*4;                   // 4 channels per lane
  const float4 av = *(const float4*)(att + c0);
  const f32x2 avlo = {av.x, av.y}, avhi = {av.z, av.w};
  float ss0=0.f, ss1=0.f, ss2=0.f, ss3=0.f;
  float qq0=0.f, qq1=0.f, qq2=0.f, qq3=0.f;

  for (int k = 0; k < 2; k++){
    const int node = blockIdx.x*8 + wave*4 + k*2 + half;    // < N_NODES (grid exact)
    const uint2 xru = *(const uint2*)(xr_aggr + (size_t)node*64 + l32*2);
    const f32x2 xr0 = bp2v(xru.x), xr1 = bp2v(xru.y);
    f32x2 acc0 = {0.f,0.f}, acc1 = {0.f,0.f};
    float den = 0.f;
    const int beg = offsets[node], end = offsets[node+1];
    int it = (end - beg + 3) >> 2;
    int oit = __shfl_xor(it, 32);
    const int maxit = it > oit ? it : oit;
    int i = beg;
    for (int n = 0; n < maxit; n++, i += 4){
      const int mm = end - i;
      int ib = (mm > 0) ? i : beg;
      ib = ib < N_EDGES ? ib : N_EDGES - 1;
      const int i0 = ib;
      const int i1 = (mm > 1) ? i+1 : ib;
      const int i2 = (mm > 2) ? i+2 : ib;
      const int i3 = (mm > 3) ? i+3 : ib;
      const int s0 = ssrc[i0], s1 = ssrc[i1], s2 = ssrc[i2], s3 = ssrc[i3];
      const uint2 e0 = *(const uint2*)(eproj + (size_t)i0*128 + c0);
      const uint2 e1 = *(const uint2*)(eproj + (size_t)i1*128 + c0);
      const uint2 e2 = *(const uint2*)(eproj + (size_t)i2*128 + c0);
      const uint2 e3 = *(const uint2*)(eproj + (size_t)i3*128 + c0);
      const uint2 x0 = *(const uint2*)(xl + (size_t)s0*HID_ + c0);
      const uint2 x1 = *(const uint2*)(xl + (size_t)s1*HID_ + c0);
      const uint2 x2 = *(const uint2*)(xl + (size_t)s2*HID_ + c0);
      const uint2 x3 = *(const uint2*)(xl + (size_t)s3*HID_ + c0);
      const f32x2 vl00 = bp2v(x0.x), vl01 = bp2v(x0.y);
      const f32x2 vl10 = bp2v(x1.x), vl11 = bp2v(x1.y);
      const f32x2 vl20 = bp2v(x2.x), vl21 = bp2v(x2.y);
      const f32x2 vl30 = bp2v(x3.x), vl31 = bp2v(x3.y);
      f32x2 v00 = vl00 + xr0 + bp2v(e0.x), v01 = vl01 + xr1 + bp2v(e0.y);
      f32x2 v10 = vl10 + xr0 + bp2v(e1.x), v11 = vl11 + xr1 + bp2v(e1.y);
      f32x2 v20 = vl20 + xr0 + bp2v(e2.x), v21 = vl21 + xr1 + bp2v(e2.y);
      f32x2 v30 = vl30 + xr0 + bp2v(e3.x), v31 = vl31 + xr1 + bp2v(e3.y);
      v00 = pmax2(v00, v00*0.2f); v01 = pmax2(v01, v01*0.2f);
      v10 = pmax2(v10, v10*0.2f); v11 = pmax2(v11, v11*0.2f);
      v20 = pmax2(v20, v20*0.2f); v21 = pmax2(v21, v21*0.2f);
      v30 = pmax2(v30, v30*0.2f); v31 = pmax2(v31, v31*0.2f);
      f32x2 ps0 = v00*avlo + v01*avhi;
      f32x2 ps1 = v10*avlo + v11*avhi;
      f32x2 ps2 = v20*avlo + v21*avhi;
      f32x2 ps3 = v30*avlo + v31*avhi;
      float sc0 = ps0.x + ps0.y;
      float sc1 = ps1.x + ps1.y;
      float sc2 = ps2.x + ps2.y;
      float sc3 = ps3.x + ps3.y;
      sc0 += __shfl_xor(sc0, 1); sc1 += __shfl_xor(sc1, 1); sc2 += __shfl_xor(sc2, 1); sc3 += __shfl_xor(sc3, 1);
      sc0 += __shfl_xor(sc0, 2); sc1 += __shfl_xor(sc1, 2); sc2 += __shfl_xor(sc2, 2); sc3 += __shfl_xor(sc3, 2);
      sc0 += __shfl_xor(sc0, 4); sc1 += __shfl_xor(sc1, 4); sc2 += __shfl_xor(sc2, 4); sc3 += __shfl_xor(sc3, 4);
      const float p0 = (mm > 0) ? __expf(sc0) : 0.f;
      const float p1 = (mm > 1) ? __expf(sc1) : 0.f;
      const float p2 = (mm > 2) ? __expf(sc2) : 0.f;
      const float p3 = (mm > 3) ? __expf(sc3) : 0.f;
      acc0 += p0*vl00 + p1*vl10 + p2*vl20 + p3*vl30;
      acc1 += p0*vl01 + p1*vl11 + p2*vl21 + p3*vl31;
      den  += p0 + p1 + p2 + p3;
    }
    const float inv = 1.0f / (den + 1e-16f);
    uint2 outv;
    outv.x = packbf(acc0.x*inv, acc0.y*inv);
    outv.y = packbf(acc1.x*inv, acc1.y*inv);
    *(uint2*)(xr_aggr + (size_t)node*64 + l32*2) = outv;
    const float2 o0 = bp2f(outv.x), o1 = bp2f(outv.y);
    ss0 += o0.x; ss1 += o0.y; ss2 += o1.x; ss3 += o1.y;
    qq0 += o0.x*o0.x; qq1 += o0.y*o0.y; qq2 += o1.x*o1.x; qq3 += o1.y*o1.y;
  }
  const int g = wave*2 + half;            // 0..3
  red[g][c0+0] = ss0; red[g][c0+1] = ss1; red[g][c0+2] = ss2; red[g][c0+3] = ss3;
  red[g][128+c0+0] = qq0; red[g][128+c0+1] = qq1; red[g][128+c0+2] = qq2; red[g][128+c0+3] = qq3;
  __syncthreads();
  {
    float a = 0.f, b2 = 0.f;
    #pragma unroll
    for (int gg = 0; gg < 4; gg++){ a += red[gg][t]; b2 += red[gg][128+t]; }
    const int base = (blockIdx.x & (NSTRIPE-1))*256;   // 32-way stripe
    atomicAdd(&stats[base + t],       a);
    atomicAdd(&stats[base + 128 + t], b2);
  }
}

// ---------------- BN apply + ELU (+ residual): pre-reduce 32 stripes + scale/shift in LDS ----------------
__global__ __launch_bounds__(256) void k_bn_apply(const unsigned* __restrict__ aggr_b,
                                                  const float* __restrict__ stats,
                                                  const float* __restrict__ gamma,
                                                  const float* __restrict__ beta,
                                                  u16* __restrict__ h, int residual){
  __shared__ float sc_sh[128], sh_sh[128];
  const int t = threadIdx.x;
  if (t < 128){
    float s = 0.f, q = 0.f;
    #pragma unroll
    for (int st = 0; st < NSTRIPE; st++){
      s += stats[st*256 + t];
      q += stats[st*256 + 128 + t];
    }
    const float invn = 1.0f / (float)N_NODES;
    float mu = s * invn;
    float var = q * invn - mu*mu;
    float sc = rsqrtf(var + 1e-5f) * gamma[t];
    sc_sh[t] = sc;
    sh_sh[t] = beta[t] - mu * sc;
  }
  __syncthreads();
  size_t i = (size_t)blockIdx.x*256 + t;   // uint4-group index (8 channels)
  if (i >= (size_t)N_NODES*16) return;
  const int c = (int)((i & 15) * 8);
  uint4 v4 = ((const uint4*)aggr_b)[i];
  uint4* hp = (uint4*)h + i;
  uint4 hv4 = make_uint4(0,0,0,0);
  if (residual) hv4 = *hp;
  unsigned vin[4]  = {v4.x, v4.y, v4.z, v4.w};
  unsigned hin[4]  = {hv4.x, hv4.y, hv4.z, hv4.w};
  unsigned outw[4];
  #pragma unroll
  for (int j=0;j<4;j++){
    int cc = c + j*2;
    float2 v = bp2f(vin[j]);
    float val0 = v.x * sc_sh[cc]   + sh_sh[cc];
    float val1 = v.y * sc_sh[cc+1] + sh_sh[cc+1];
    val0 = val0 > 0.f ? val0 : expm1f(val0);
    val1 = val1 > 0.f ? val1 : expm1f(val1);
    if (residual){
      float2 hv = bp2f(hin[j]);
      val0 += hv.x; val1 += hv.y;
    }
    outw[j] = packbf(val0, val1);
  }
  *hp = make_uint4(outw[0], outw[1], outw[2], outw[3]);
}

// ---------------- Pool: segmented mean (1024 blocks) ----------------
__global__ __launch_bounds__(256) void k_pool_seg(const unsigned* __restrict__ h2,
                                                  const int* __restrict__ goff,
                                                  float* __restrict__ emb){
  __shared__ float redS[4][128];
  const int g = blockIdx.x, t = threadIdx.x;
  const int p = t & 63, rg = t >> 6;
  const int beg = goff[g], end = goff[g+1];
  float a0 = 0.f, a1 = 0.f;
  for (int r = beg + rg; r < end; r += 4){
    float2 v = bp2f(h2[(size_t)r*64 + p]);
    a0 += v.x; a1 += v.y;
  }
  redS[rg][p*2] = a0; redS[rg][p*2+1] = a1;
  __syncthreads();
  if (rg == 0){
    #pragma unroll
    for (int k=1;k<4;k++){ a0 += redS[k][p*2]; a1 += redS[k][p*2+1]; }
    float n = fmaxf((float)(end - beg), 1.f);
    emb[(size_t)g*HID_ + p*2]     = a0 / n;
    emb[(size_t)g*HID_ + p*2 + 1] = a1 / n;
  }
}

// ---------------- Per-task heads: 8 graphs per block, (128,5) grid ----------------
#define HG 8
__global__ __launch_bounds__(128) void k_heads(const float* __restrict__ emb,
                                               const float* __restrict__ mf,
                                               const int* __restrict__ fpi,
                                               const float* __restrict__ tw1,
                                               const float* __restrict__ tb1,
                                               const float* __restrict__ tw2,
                                               const float* __restrict__ tb2,
                                               float* __restrict__ out){
  const int task = blockIdx.y, g0 = blockIdx.x*HG;
  const int j = threadIdx.x;
  __shared__ float fused[HG][160];
  __shared__ float red[HG][128];
  for (int idx = j; idx < HG*160; idx += 128){
    int g = idx / 160, i = idx % 160;
    float v;
    if (i < 128) v = emb[(size_t)(g0+g)*HID_ + i];
    else         v = mf[(size_t)(g0+g)*2048 + fpi[task*32 + (i-128)]];
    fused[g][i] = v;
  }
  __syncthreads();
  const float* w1 = tw1 + (size_t)task*160*128;
  float acc[HG];
  float b1 = tb1[task*128 + j];
  #pragma unroll
  for (int g=0; g<HG; g++) acc[g] = b1;
  for (int i=0; i<160; i++){
    float wv = w1[(size_t)i*128 + j];
    #pragma unroll
    for (int g=0; g<HG; g++) acc[g] += fused[g][i] * wv;
  }
  float t2 = tw2[task*128 + j];
  #pragma unroll
  for (int g=0; g<HG; g++){
    float v = acc[g] > 0.f ? acc[g] : 0.f;
    red[g][j] = v * t2;
  }
  __syncthreads();
  int g = j >> 4, l16 = j & 15;
  float s = 0.f;
  #pragma unroll
  for (int k=0;k<8;k++) s += red[g][l16 + k*16];
  s += __shfl_xor(s, 1, 16);
  s += __shfl_xor(s, 2, 16);
  s += __shfl_xor(s, 4, 16);
  s += __shfl_xor(s, 8, 16);
  if (l16 == 0) out[(size_t)(g0+g)*N_TASK + task] = s + tb2[task];
}

extern "C" void kernel_launch(void* const* d_in, const int* in_sizes, int n_in,
                              void* d_out, int out_size, void* d_ws, size_t ws_size,
                              hipStream_t stream){
  const float* x    = (const float*)d_in[0];
  const int*   ei   = (const int*)  d_in[1];
  const float* ea   = (const float*)d_in[2];
  const int*   batch= (const int*)  d_in[3];
  const float* mf   = (const float*)d_in[4];
  const int*   fpi  = (const int*)  d_in[5];
  const float* Wl0  = (const float*)d_in[6];
  const float* bl0  = (const float*)d_in[7];
  const float* Wr0  = (const float*)d_in[8];
  const float* br0  = (const float*)d_in[9];
  const float* We0  = (const float*)d_in[10];
  const float* att0 = (const float*)d_in[11];
  const float* g0   = (const float*)d_in[13];
  const float* b0   = (const float*)d_in[14];
  const float* Wl   = (const float*)d_in[15];
  const float* bl   = (const float*)d_in[16];
  const float* Wr   = (const float*)d_in[17];
  const float* br   = (const float*)d_in[18];
  const float* We   = (const float*)d_in[19];
  const float* att  = (const float*)d_in[20];
  const float* gg   = (const float*)d_in[22];
  const float* bb   = (const float*)d_in[23];
  const float* tw1  = (const float*)d_in[24];
  const float* tb1  = (const float*)d_in[25];
  const float* tw2  = (const float*)d_in[26];
  const float* tb2  = (const float*)d_in[27];
  float* out = (float*)d_out;

  char* w = (char*)d_ws;
  auto alloc = [&](size_t bytes)->char*{ char* r = w; w += (bytes + 255) & ~(size_t)255; return r; };
  u16*   xl     = (u16*)  alloc((size_t)N_NODES*HID_*2);
  unsigned* xr_aggr = (unsigned*)alloc((size_t)N_NODES*64*4);
  u16*   h      = (u16*)  alloc((size_t)N_NODES*HID_*2);
  u16*   ea16   = (u16*)  alloc((size_t)N_EDGES*16*2);
  int*   counts = (int*)  alloc((size_t)N_NODES*4);
  float* stats4 = (float*)alloc(4*NSTRIPE*256*4);      // 4 layers x 32 stripes x 256 floats
  int*   offsets= (int*)  alloc((size_t)(N_NODES+1)*4);
  int*   cursor = (int*)  alloc((size_t)N_NODES*4);
  int*   incl   = (int*)  alloc((size_t)N_NODES*4);
  int*   bsum   = (int*)  alloc(256*4);
  int*   ssrc   = (int*)  alloc((size_t)N_EDGES*4);
  int*   goff   = (int*)  alloc((size_t)(N_GRAPH+1)*4);
  float* emb    = (float*)alloc((size_t)N_GRAPH*HID_*4);
  u16*   Wzl0   = (u16*)  alloc((size_t)F_NODE_*128*2);
  u16*   Wzr0   = (u16*)  alloc((size_t)F_NODE_*128*2);
  u16*   Wzl123 = (u16*)  alloc((size_t)3*HID_*128*2);
  u16*   Wzr123 = (u16*)  alloc((size_t)3*HID_*128*2);
  u16*   Wez4   = (u16*)  alloc((size_t)4*32*128*2);
  u16*   eproj  = (u16*)  alloc((size_t)N_EDGES*HID_*2);
  u16*   xbf    = (u16*)  alloc((size_t)N_NODES*F_NODE_*2);  // separate from eproj (no race)

  const size_t zlen = (size_t)((char*)(stats4 + 4*NSTRIPE*256) - (char*)counts);
  const int nscan = (N_NODES + 511)/512;

  WZ12 p;
  p.src[0] = Wl0; p.dst[0] = Wzl0; p.Ks[0] = F_NODE_; p.Kd[0] = F_NODE_;
  p.src[1] = Wr0; p.dst[1] = Wzr0; p.Ks[1] = F_NODE_; p.Kd[1] = F_NODE_;
  for (int i=0;i<3;i++){
    p.src[2+i] = Wl + (size_t)i*HID_*HID_; p.dst[2+i] = Wzl123 + (size_t)i*HID_*128; p.Ks[2+i] = HID_; p.Kd[2+i] = HID_;
    p.src[5+i] = Wr + (size_t)i*HID_*HID_; p.dst[5+i] = Wzr123 + (size_t)i*HID_*128; p.Ks[5+i] = HID_; p.Kd[5+i] = HID_;
  }
  p.src[8] = We0; p.dst[8] = Wez4; p.Ks[8] = F_EDGE_; p.Kd[8] = 32;
  for (int i=0;i<3;i++){
    p.src[9+i] = We + (size_t)i*F_EDGE_*HID_; p.dst[9+i] = Wez4 + (size_t)(i+1)*32*128; p.Ks[9+i] = F_EDGE_; p.Kd[9+i] = 32;
  }

  hipMemsetAsync(counts, 0, zlen, stream);
  hipLaunchKernelGGL(k_cast_hist, dim3(CAST_BLKS + EG256 + GOFF_BLKS + WSWZ_BLKS), dim3(256), 0, stream,
                     x, xbf, ei, counts, batch, goff, p);
  hipLaunchKernelGGL(k_scan1,  dim3(nscan), dim3(512), 0, stream, counts, incl, bsum);
  hipLaunchKernelGGL(k_scan3,  dim3(nscan), dim3(512), 0, stream, counts, incl, bsum, nscan, offsets, cursor);
  hipLaunchKernelGGL(k_scatter,dim3(EG256), dim3(256), 0, stream, ei, cursor, ssrc, ea, ea16);

  for (int layer = 0; layer < 4; layer++){
    const float *bl_, *br_, *att_, *g_, *b_;
    const u16 *Wzl_, *Wzr_, *Ain;
    int K;
    if (layer == 0){
      bl_=bl0; br_=br0; att_=att0; g_=g0; b_=b0;
      Wzl_ = Wzl0; Wzr_ = Wzr0; Ain = xbf; K = F_NODE_;
    } else {
      int i = layer - 1;
      bl_ = bl + (size_t)i*HID_;  br_ = br + (size_t)i*HID_;
      att_= att + (size_t)i*HID_;
      g_  = gg + (size_t)i*HID_;  b_  = bb + (size_t)i*HID_;
      Wzl_ = Wzl123 + (size_t)i*HID_*128;
      Wzr_ = Wzr123 + (size_t)i*HID_*128;
      Ain = h; K = HID_;
    }
    float* stats = stats4 + (size_t)layer*NSTRIPE*256;
    hipLaunchKernelGGL(k_gemm_eproj, dim3(2*GEMM_GRID + EPROJ_GRID), dim3(256), 0, stream,
                       Ain, Wzl_, Wzr_, bl_, br_, xl, (u16*)xr_aggr, N_NODES, K,
                       ea16, Wez4 + (size_t)layer*32*128, eproj);
    hipLaunchKernelGGL(k_gat_ep, dim3(GAT_GRID), dim3(128), 0, stream,
                       xl, xr_aggr, eproj, att_, offsets, ssrc, stats);
    hipLaunchKernelGGL(k_bn_apply, dim3((N_NODES*16 + 255)/256), dim3(256), 0, stream,
                       xr_aggr, stats, g_, b_, h, layer > 0 ? 1 : 0);
  }
  hipLaunchKernelGGL(k_pool_seg, dim3(N_GRAPH), dim3(256), 0, stream, (const unsigned*)h, goff, emb);
  hipLaunchKernelGGL(k_heads, dim3(N_GRAPH/HG, N_TASK), dim3(128), 0, stream, emb, mf, fpi, tw1, tb1, tw2, tb2, out);
}